// Round 6
// baseline (75284.033 us; speedup 1.0000x reference)
//
#include <hip/hip_runtime.h>

#define NWG 512
#define WGS 512

typedef __attribute__((ext_vector_type(4))) float facc4;
typedef __attribute__((ext_vector_type(8))) short bfrag8;

#define MFMA_BF16 __builtin_amdgcn_mfma_f32_16x16x32_bf16

constexpr int B_ = 128, T_ = 512, I_ = 128, H_ = 1024;
constexpr int G_ = 4 * H_;  // 4096

// ---------------- workspace layout (bytes) ----------------
constexpr size_t OFF_BAR  = 0;       // device-wide barrier (64 leaves)
constexpr size_t OFF_GRP  = 8448;    // 16 lane barriers x 768 B
constexpr size_t OFF_FLG  = 20736;   // aProg[8]/bProg[8], 128B lines
constexpr size_t OFF_H1F  = 24576;
constexpr size_t OFF_H2F  = OFF_H1F + 2ull * B_ * H_ * 4;
constexpr size_t OFF_C1   = OFF_H2F + 2ull * B_ * H_ * 4;
constexpr size_t OFF_C2   = OFF_C1 + (size_t)B_ * H_ * 4;
constexpr size_t OFF_X1F  = OFF_C2 + (size_t)B_ * H_ * 4;
constexpr size_t OFF_X2F  = OFF_X1F + (size_t)B_ * I_ * 4;
constexpr size_t OFF_H1S  = OFF_X2F + (size_t)B_ * H_ * 4;
constexpr size_t OFF_H2S  = OFF_H1S + 2ull * B_ * H_ * 2;
constexpr size_t OFF_X1S  = OFF_H2S + 2ull * B_ * H_ * 2;
constexpr size_t OFF_X2S  = OFF_X1S + (size_t)B_ * I_ * 2;
constexpr size_t OFF_BS1  = OFF_X2S + (size_t)B_ * H_ * 2;
constexpr size_t OFF_BS2  = OFF_BS1 + (size_t)G_ * 4;
constexpr size_t ZERO_BYTES = OFF_BS2 + (size_t)G_ * 4;
// bf16 weights (converted in-kernel each launch), L2-resident afterwards
constexpr size_t OFF_WQ1  = ZERO_BYTES;                         // 3*I*H
constexpr size_t OFF_WR1  = OFF_WQ1 + 3ull * I_ * H_ * 2;       // 2*H*I
constexpr size_t OFF_WIH1 = OFF_WR1 + 2ull * H_ * I_ * 2;       // G*I
constexpr size_t OFF_WHH1 = OFF_WIH1 + (size_t)G_ * I_ * 2;     // G*H
constexpr size_t OFF_WQ2  = OFF_WHH1 + (size_t)G_ * H_ * 2;     // 3*H*H
constexpr size_t OFF_WR2  = OFF_WQ2 + 3ull * H_ * H_ * 2;       // 2*H*H
constexpr size_t OFF_WIH2 = OFF_WR2 + 2ull * H_ * H_ * 2;       // G*H
constexpr size_t OFF_WHH2 = OFF_WIH2 + (size_t)G_ * H_ * 2;     // G*H

// ---------------- dynamic LDS (sized for 2 WGs/CU) ----------------
// A-staging: 16 rows x 1160 els (covers cell1 K=1152; cell2 staged in two
// 1024-chunks; mog K=1024 @ stride 1032; mog1R 128 rows @ stride 136).
// Strides == 16 B (mod 128 B) -> 2-way bank aliasing only (free).
constexpr size_t A_OFF   = 0;                    // 16*1160*2 = 37120
constexpr size_t RED_OFF = 37120;                // 8*2*4*64*4 = 16384
constexpr size_t DYN_LDS = RED_OFF + 16384;      // 53504  (x2 = 107 KB < 160)

struct GBar {
  unsigned leaf[64][32];  // one counter per 128B line (512 WGs: 64 x 8)
  unsigned root[32];
  unsigned gen[32];
};
// per-lane barrier: 32 WGs = 4 leaves x 8, root counts 4. 768 B each.
struct GrpBar {
  unsigned leaf[4][32];
  unsigned root[32];
  unsigned gen[32];
};

__device__ __forceinline__ float sigf(float x) { return 1.0f / (1.0f + __expf(-x)); }

__device__ __forceinline__ unsigned short f2bf(float f) {
  union { float f; unsigned u; } v; v.f = f;
  unsigned r = v.u + 0x7FFFu + ((v.u >> 16) & 1u);  // RNE
  return (unsigned short)(r >> 16);
}

// ---------- device-coherent (sc0 sc1) data plane for cross-WG data ----------
__device__ __forceinline__ float cloadf(const float* p) {
  return __hip_atomic_load(p, __ATOMIC_RELAXED, __HIP_MEMORY_SCOPE_AGENT);
}
__device__ __forceinline__ void cstoref(float* p, float v) {
  __hip_atomic_store(p, v, __ATOMIC_RELAXED, __HIP_MEMORY_SCOPE_AGENT);
}
__device__ __forceinline__ void cstoreu(unsigned* p, unsigned v) {
  __hip_atomic_store(p, v, __ATOMIC_RELAXED, __HIP_MEMORY_SCOPE_AGENT);
}
// pack bf16 shadow pairs: even lane stores (v, neighbor v) as one u32
__device__ __forceinline__ void cstore_sh(unsigned short* base, size_t idx, float v, int lane) {
  float vo = __shfl_xor(v, 1);
  if (!(lane & 1)) {
    unsigned pk = (unsigned)f2bf(v) | ((unsigned)f2bf(vo) << 16);
    cstoreu((unsigned*)(base + idx), pk);
  }
}

// bulk coherent stage (activations): rows x (C4*4) bf16 -> LDS, whole WG
template <int C4>
__device__ __forceinline__ void stage_coh(unsigned short* lds, int ldsStride, int ldsColOff,
                                          const unsigned short* src, int srcStride, int rows) {
  const int total = rows * C4;
  for (int i = threadIdx.x; i < total; i += WGS) {
    int r = i / C4, q = (i % C4) * 4;
    unsigned long long v = __hip_atomic_load(
        (const unsigned long long*)(src + (size_t)r * srcStride + q),
        __ATOMIC_RELAXED, __HIP_MEMORY_SCOPE_AGENT);
    *(unsigned long long*)(lds + (size_t)r * ldsStride + ldsColOff + q) = v;
  }
}

// ---- per-lane fence-free barrier (32 WGs). Visibility argument as round 0:
// __syncthreads drains vmcnt (coherent stores at L3); all cross-WG data agent-scope.
__device__ __forceinline__ void gbar_grp(GrpBar* b, int l) {
  __syncthreads();
  if (threadIdx.x == 0) {
    unsigned g = __hip_atomic_load(&b->gen[0], __ATOMIC_RELAXED, __HIP_MEMORY_SCOPE_AGENT);
    unsigned a = __hip_atomic_fetch_add(&b->leaf[l >> 3][0], 1u, __ATOMIC_RELAXED,
                                        __HIP_MEMORY_SCOPE_AGENT);
    if (a == 7u) {
      unsigned r = __hip_atomic_fetch_add(&b->root[0], 1u, __ATOMIC_RELAXED,
                                          __HIP_MEMORY_SCOPE_AGENT);
      if (r == 3u) {
        for (int i = 0; i < 4; i++)
          __hip_atomic_store(&b->leaf[i][0], 0u, __ATOMIC_RELAXED, __HIP_MEMORY_SCOPE_AGENT);
        __hip_atomic_store(&b->root[0], 0u, __ATOMIC_RELAXED, __HIP_MEMORY_SCOPE_AGENT);
        __hip_atomic_store(&b->gen[0], g + 1u, __ATOMIC_RELEASE, __HIP_MEMORY_SCOPE_AGENT);
      }
    }
    while (__hip_atomic_load(&b->gen[0], __ATOMIC_RELAXED, __HIP_MEMORY_SCOPE_AGENT) == g)
      __builtin_amdgcn_s_sleep(1);
    asm volatile("" ::: "memory");
  }
  __syncthreads();
}

// ---- cross-lane progress flags (once per step, one L3 line each)
__device__ __forceinline__ void wait_flag(unsigned* f, unsigned need) {
  if (threadIdx.x == 0) {
    while (__hip_atomic_load(f, __ATOMIC_RELAXED, __HIP_MEMORY_SCOPE_AGENT) < need)
      __builtin_amdgcn_s_sleep(1);
    asm volatile("" ::: "memory");
  }
  __syncthreads();
}

// ---- device-wide full-fence barrier: init (publish weights) + final collect
__device__ __forceinline__ void gbar_full(GBar* b) {
  __syncthreads();
  if (threadIdx.x == 0) {
    __builtin_amdgcn_fence(__ATOMIC_RELEASE, "agent");
    unsigned g = __hip_atomic_load(&b->gen[0], __ATOMIC_RELAXED, __HIP_MEMORY_SCOPE_AGENT);
    int leaf = blockIdx.x >> 3;  // 64 leaves x 8 WGs
    unsigned a = __hip_atomic_fetch_add(&b->leaf[leaf][0], 1u, __ATOMIC_RELAXED,
                                        __HIP_MEMORY_SCOPE_AGENT);
    if (a == 7u) {
      unsigned r = __hip_atomic_fetch_add(&b->root[0], 1u, __ATOMIC_RELAXED,
                                          __HIP_MEMORY_SCOPE_AGENT);
      if (r == 63u) {
        for (int i = 0; i < 64; i++)
          __hip_atomic_store(&b->leaf[i][0], 0u, __ATOMIC_RELAXED, __HIP_MEMORY_SCOPE_AGENT);
        __hip_atomic_store(&b->root[0], 0u, __ATOMIC_RELAXED, __HIP_MEMORY_SCOPE_AGENT);
        __hip_atomic_store(&b->gen[0], g + 1u, __ATOMIC_RELEASE, __HIP_MEMORY_SCOPE_AGENT);
      }
    }
    while (__hip_atomic_load(&b->gen[0], __ATOMIC_RELAXED, __HIP_MEMORY_SCOPE_AGENT) == g)
      __builtin_amdgcn_s_sleep(1);
    __builtin_amdgcn_fence(__ATOMIC_ACQUIRE, "agent");
  }
  __syncthreads();
}

// ---- wave-local mog unit (round-4/5 verified): wave wv computes ONE 16x16
// tile (nt = ntBase+wv), FULL K. A staged coherent; W per-lane cached (<=32KB).
// acc[j] -> (m = mt*16 + lq*4 + j, n = nt*16 + l15)
template <int K>
__device__ __forceinline__ void mog_wl(
    const unsigned short* __restrict__ A,   // bf16 shadow, row stride K
    const unsigned short* __restrict__ W,   // N rows x K, plain-cached
    const float* __restrict__ bias,
    const float* srcF, int srcStride,
    float* dstF, unsigned short* dstS, int N,
    int mt, int ntBase, unsigned short* As) {
  const int tid = threadIdx.x, lane = tid & 63, wv = tid >> 6;
  const int l15 = lane & 15, lq = lane >> 4;
  const int nt = ntBase + wv, n = nt * 16 + l15;
  constexpr int LSTR = K + 8;
  float srcv[4];
#pragma unroll
  for (int j = 0; j < 4; j++)
    srcv[j] = cloadf(&srcF[(size_t)(mt * 16 + lq * 4 + j) * srcStride + n]);
  const float bn = bias[n];

  stage_coh<K / 4>(As, LSTR, 0, A + (size_t)(mt * 16) * K, K, 16);
  __syncthreads();

  const unsigned short* ap = As + l15 * LSTR + lq * 8;
  const unsigned short* wp = W + (size_t)n * K + lq * 8;
  facc4 acc = {0.f, 0.f, 0.f, 0.f};
#pragma unroll 8
  for (int k = 0; k < K; k += 32)
    acc = MFMA_BF16(*(const bfrag8*)(ap + k), *(const bfrag8*)(wp + k), acc, 0, 0, 0);
#pragma unroll
  for (int j = 0; j < 4; j++) {
    float v = 2.0f * sigf(acc[j] + bn) * srcv[j];
    const int m = mt * 16 + lq * 4 + j;
    cstoref(&dstF[(size_t)m * N + n], v);
    cstore_sh(dstS, (size_t)m * N + n, v, lane);
  }
  // trailing sync provided by the lane barrier
}

// ---- LSTM cell unit (round-4/5 verified bodies; cell2 A staged in 2 chunks
// to fit the 37 KB buffer). WG = (mt, nb<16) -> 16 rows x 64 H-cols.
// 8 waves = 4 gates x 2 col-halves; gate exchange via LDS red.
template <int CELL>
__device__ __forceinline__ void cell_wl(
    const unsigned short* __restrict__ Xs,
    const unsigned short* __restrict__ Hs,
    const unsigned short* __restrict__ Wih,
    const unsigned short* __restrict__ Whh,
    const float* __restrict__ bsum,
    float* cst, float* hF, unsigned short* hS,
    int mt, int nb, unsigned short* As, float (*red)[2][4][64]) {
  constexpr int KX = (CELL == 1) ? 128 : 1024;
  constexpr int LSTR = 1160;
  const int tid = threadIdx.x, lane = tid & 63, wv = tid >> 6;
  const int l15 = lane & 15, lq = lane >> 4;
  const int g = wv >> 1, nh = wv & 1;
  const int n0 = nb * 64 + nh * 32 + l15;
  const int n1 = n0 + 16;

  float cold[2][4];
  float bsv[2][4];
  if (g == 0) {
#pragma unroll
    for (int j = 0; j < 4; j++) {
      cold[0][j] = cloadf(&cst[(size_t)(mt * 16 + lq * 4 + j) * H_ + n0]);
      cold[1][j] = cloadf(&cst[(size_t)(mt * 16 + lq * 4 + j) * H_ + n1]);
    }
#pragma unroll
    for (int gg = 0; gg < 4; gg++) {
      bsv[0][gg] = bsum[gg * H_ + n0];
      bsv[1][gg] = bsum[gg * H_ + n1];
    }
  }

  const unsigned short* ap = As + l15 * LSTR + lq * 8;
  const int wr0 = g * H_ + nb * 64 + nh * 32 + l15;
  const unsigned short* wi0 = Wih + (size_t)wr0 * KX + lq * 8;
  const unsigned short* wi1 = wi0 + (size_t)16 * KX;
  const unsigned short* wh0 = Whh + (size_t)wr0 * 1024 + lq * 8;
  const unsigned short* wh1 = wh0 + (size_t)16 * 1024;
  facc4 a0 = {0.f, 0.f, 0.f, 0.f}, a1 = {0.f, 0.f, 0.f, 0.f};

  if (CELL == 1) {
    stage_coh<KX / 4>(As, LSTR, 0, Xs + (size_t)(mt * 16) * KX, KX, 16);
    stage_coh<256>(As, LSTR, KX, Hs + (size_t)(mt * 16) * 1024, 1024, 16);
    __syncthreads();
#pragma unroll 4
    for (int k = 0; k < KX; k += 32) {
      bfrag8 af = *(const bfrag8*)(ap + k);
      a0 = MFMA_BF16(af, *(const bfrag8*)(wi0 + k), a0, 0, 0, 0);
      a1 = MFMA_BF16(af, *(const bfrag8*)(wi1 + k), a1, 0, 0, 0);
    }
#pragma unroll 4
    for (int k = 0; k < 1024; k += 32) {
      bfrag8 af = *(const bfrag8*)(ap + KX + k);
      a0 = MFMA_BF16(af, *(const bfrag8*)(wh0 + k), a0, 0, 0, 0);
      a1 = MFMA_BF16(af, *(const bfrag8*)(wh1 + k), a1, 0, 0, 0);
    }
  } else {
    // chunk 1: x2s (K=1024) -> Wih part
    stage_coh<256>(As, LSTR, 0, Xs + (size_t)(mt * 16) * 1024, 1024, 16);
    __syncthreads();
#pragma unroll 4
    for (int k = 0; k < 1024; k += 32) {
      bfrag8 af = *(const bfrag8*)(ap + k);
      a0 = MFMA_BF16(af, *(const bfrag8*)(wi0 + k), a0, 0, 0, 0);
      a1 = MFMA_BF16(af, *(const bfrag8*)(wi1 + k), a1, 0, 0, 0);
    }
    __syncthreads();
    // chunk 2: h2s (K=1024) -> Whh part
    stage_coh<256>(As, LSTR, 0, Hs + (size_t)(mt * 16) * 1024, 1024, 16);
    __syncthreads();
#pragma unroll 4
    for (int k = 0; k < 1024; k += 32) {
      bfrag8 af = *(const bfrag8*)(ap + k);
      a0 = MFMA_BF16(af, *(const bfrag8*)(wh0 + k), a0, 0, 0, 0);
      a1 = MFMA_BF16(af, *(const bfrag8*)(wh1 + k), a1, 0, 0, 0);
    }
  }

#pragma unroll
  for (int j = 0; j < 4; j++) { red[wv][0][j][lane] = a0[j]; red[wv][1][j][lane] = a1[j]; }
  __syncthreads();

  if (g == 0) {
#pragma unroll
    for (int tt = 0; tt < 2; tt++) {
      const int n = (tt == 0) ? n0 : n1;
#pragma unroll
      for (int j = 0; j < 4; j++) {
        float di = red[0 * 2 + nh][tt][j][lane];
        float df = red[1 * 2 + nh][tt][j][lane];
        float dg = red[2 * 2 + nh][tt][j][lane];
        float dd = red[3 * 2 + nh][tt][j][lane];
        float iv = sigf(di + bsv[tt][0]);
        float fv = sigf(df + bsv[tt][1]);
        float gv = tanhf(dg + bsv[tt][2]);
        float ov = sigf(dd + bsv[tt][3]);
        float cn = fv * cold[tt][j] + iv * gv;
        float hn = ov * tanhf(cn);
        const int m = mt * 16 + lq * 4 + j;
        const size_t idx = (size_t)m * H_ + n;
        cstoref(&cst[idx], cn);
        cstoref(&hF[idx], hn);
        cstore_sh(hS, idx, hn, lane);
      }
    }
  }
}

__global__ __launch_bounds__(WGS, 4) void moglstm_kernel(
    const float* __restrict__ in_seq,
    const float* __restrict__ c1Q, const float* __restrict__ c1Qb,
    const float* __restrict__ c1R, const float* __restrict__ c1Rb,
    const float* __restrict__ c1Wih, const float* __restrict__ c1Whh,
    const float* __restrict__ c1bih, const float* __restrict__ c1bhh,
    const float* __restrict__ c2Q, const float* __restrict__ c2Qb,
    const float* __restrict__ c2R, const float* __restrict__ c2Rb,
    const float* __restrict__ c2Wih, const float* __restrict__ c2Whh,
    const float* __restrict__ c2bih, const float* __restrict__ c2bhh,
    const float* __restrict__ linW, const float* __restrict__ linb,
    char* ws, float* __restrict__ out) {
  extern __shared__ char dynlds[];
  unsigned short* As = (unsigned short*)(dynlds + A_OFF);
  float (*red)[2][4][64] = reinterpret_cast<float(*)[2][4][64]>(dynlds + RED_OFF);

  GBar* bar = (GBar*)(ws + OFF_BAR);
  GrpBar* gbars = (GrpBar*)(ws + OFF_GRP);
  unsigned* aProg = (unsigned*)(ws + OFF_FLG);          // [8][32]
  unsigned* bProg = aProg + 8 * 32;                     // [8][32]
  float* h1f0 = (float*)(ws + OFF_H1F);
  float* h1f1 = h1f0 + (size_t)B_ * H_;
  float* h2f0 = (float*)(ws + OFF_H2F);
  float* h2f1 = h2f0 + (size_t)B_ * H_;
  float* c1f = (float*)(ws + OFF_C1);
  float* c2f = (float*)(ws + OFF_C2);
  float* x1f = (float*)(ws + OFF_X1F);
  float* x2f = (float*)(ws + OFF_X2F);
  unsigned short* h1s0 = (unsigned short*)(ws + OFF_H1S);
  unsigned short* h1s1 = h1s0 + (size_t)B_ * H_;
  unsigned short* h2s0 = (unsigned short*)(ws + OFF_H2S);
  unsigned short* h2s1 = h2s0 + (size_t)B_ * H_;
  unsigned short* x1s = (unsigned short*)(ws + OFF_X1S);
  unsigned short* x2s = (unsigned short*)(ws + OFF_X2S);
  float* bs1 = (float*)(ws + OFF_BS1);
  float* bs2 = (float*)(ws + OFF_BS2);
  unsigned short* wq1 = (unsigned short*)(ws + OFF_WQ1);
  unsigned short* wr1 = (unsigned short*)(ws + OFF_WR1);
  unsigned short* wih1 = (unsigned short*)(ws + OFF_WIH1);
  unsigned short* whh1 = (unsigned short*)(ws + OFF_WHH1);
  unsigned short* wq2 = (unsigned short*)(ws + OFF_WQ2);
  unsigned short* wr2 = (unsigned short*)(ws + OFF_WR2);
  unsigned short* wih2 = (unsigned short*)(ws + OFF_WIH2);
  unsigned short* whh2 = (unsigned short*)(ws + OFF_WHH2);

  const int wg = blockIdx.x;

  // ---- init: fp32 -> bf16 weight conversion (plain stores) + bias sums
  {
    size_t gt = (size_t)wg * WGS + threadIdx.x;
    const size_t gs = (size_t)NWG * WGS;
    const float* srcs[8] = {c1Q, c1R, c1Wih, c1Whh, c2Q, c2R, c2Wih, c2Whh};
    unsigned short* dsts[8] = {wq1, wr1, wih1, whh1, wq2, wr2, wih2, whh2};
    const size_t cnts[8] = {3ull * I_ * H_, 2ull * H_ * I_, (size_t)G_ * I_,
                            (size_t)G_ * H_, 3ull * H_ * H_, 2ull * H_ * H_,
                            (size_t)G_ * H_, (size_t)G_ * H_};
    for (int a = 0; a < 8; a++)
      for (size_t i = gt; i < cnts[a]; i += gs) dsts[a][i] = f2bf(srcs[a][i]);
    for (size_t i = gt; i < (size_t)G_; i += gs) bs1[i] = c1bih[i] + c1bhh[i];
    for (size_t i = gt; i < (size_t)G_; i += gs) bs2[i] = c2bih[i] + c2bhh[i];
  }
  gbar_full(bar);  // full fences ONCE: publish plain-stored weights

  // Two decoupled lanes per 16-row group (grp = rows [grp*16, +16)):
  //   Lane B (wg 0..255):   layer 2, steps t=0..T-1. Reads h1f[(t+1)&1].
  //   Lane A (wg 256..511): layer 1, steps p=0..T-1. Writes h1.
  // Cross-lane sync (once per step each way):
  //   B s0(t) waits aProg >= t+1  (h1(t) complete)
  //   A s1(p) waits bProg >= p    (B consumed h1f[p&1] at its s0(p-1))
  // CU i hosts wg i and wg i+256 -> two independent phase chains per CU.
  if (wg < 256) {
    const int grp = wg >> 5, l = wg & 31;
    GrpBar* gb = &gbars[grp];
    unsigned* aP = aProg + grp * 32;
    unsigned* bP = bProg + grp * 32;
    for (int t = 0; t < T_; ++t) {
      const int cur = t & 1;
      float* h2cF = cur ? h2f1 : h2f0;
      unsigned short* h2cS = cur ? h2s1 : h2s0;
      float* h2nF = cur ? h2f0 : h2f1;
      unsigned short* h2nS = cur ? h2s0 : h2s1;
      const float* h1rd = ((t + 1) & 1) ? h1f1 : h1f0;
      // s0: Q0
      wait_flag(aP, (unsigned)(t + 1));
      if (l < 8) mog_wl<1024>(h2cS, wq2, c2Qb, h1rd, H_, x2f, x2s, H_, grp, l * 8, As);
      gbar_grp(gb, l);
      if (l == 0 && threadIdx.x == 0)
        __hip_atomic_store(bP, (unsigned)(t + 1), __ATOMIC_RELEASE, __HIP_MEMORY_SCOPE_AGENT);
      // s1: R0 (in-place h2)
      if (l < 8) mog_wl<1024>(x2s, wr2, c2Rb, h2cF, H_, h2cF, h2cS, H_, grp, l * 8, As);
      gbar_grp(gb, l);
      // s2: Q1
      if (l < 8) mog_wl<1024>(h2cS, wq2 + 1ull * H_ * H_, c2Qb + H_, x2f, H_, x2f, x2s, H_, grp, l * 8, As);
      gbar_grp(gb, l);
      // s3: R1
      if (l < 8) mog_wl<1024>(x2s, wr2 + 1ull * H_ * H_, c2Rb + H_, h2cF, H_, h2cF, h2cS, H_, grp, l * 8, As);
      gbar_grp(gb, l);
      // s4: Q2
      if (l < 8) mog_wl<1024>(h2cS, wq2 + 2ull * H_ * H_, c2Qb + 2 * H_, x2f, H_, x2f, x2s, H_, grp, l * 8, As);
      gbar_grp(gb, l);
      // s5: cell2
      if (l < 16) cell_wl<2>(x2s, h2cS, wih2, whh2, bs2, c2f, h2nF, h2nS, grp, l, As, red);
      gbar_grp(gb, l);
    }
  } else {
    const int grp = (wg >> 5) - 8, l = wg & 31;
    GrpBar* gb = &gbars[8 + grp];
    unsigned* aP = aProg + grp * 32;
    unsigned* bP = bProg + grp * 32;
    for (int p = 0; p < T_; ++p) {
      const int cur = p & 1;
      float* h1cF = cur ? h1f1 : h1f0;
      unsigned short* h1cS = cur ? h1s1 : h1s0;
      float* h1nF = cur ? h1f0 : h1f1;
      unsigned short* h1nS = cur ? h1s0 : h1s1;
      // s0: Q0 (x from in_seq)
      if (l == 8) mog_wl<1024>(h1cS, wq1, c1Qb, in_seq + (size_t)p * I_, T_ * I_, x1f, x1s, I_, grp, 0, As);
      gbar_grp(gb, l);
      // s1: R0 (in-place h1 -- gated on B having consumed this parity buffer)
      wait_flag(bP, (unsigned)p);
      if (l >= 8 && l < 16) mog_wl<128>(x1s, wr1, c1Rb, h1cF, H_, h1cF, h1cS, H_, grp, (l - 8) * 8, As);
      gbar_grp(gb, l);
      // s2: Q1
      if (l == 8) mog_wl<1024>(h1cS, wq1 + 1ull * I_ * H_, c1Qb + I_, x1f, I_, x1f, x1s, I_, grp, 0, As);
      gbar_grp(gb, l);
      // s3: R1
      if (l >= 8 && l < 16) mog_wl<128>(x1s, wr1 + 1ull * H_ * I_, c1Rb + H_, h1cF, H_, h1cF, h1cS, H_, grp, (l - 8) * 8, As);
      gbar_grp(gb, l);
      // s4: Q2
      if (l == 8) mog_wl<1024>(h1cS, wq1 + 2ull * I_ * H_, c1Qb + 2 * I_, x1f, I_, x1f, x1s, I_, grp, 0, As);
      gbar_grp(gb, l);
      // s5: cell1
      if (l < 16) cell_wl<1>(x1s, h1cS, wih1, whh1, bs1, c1f, h1nF, h1nS, grp, l, As, red);
      gbar_grp(gb, l);
      if (l == 0 && threadIdx.x == 0)
        __hip_atomic_store(aP, (unsigned)(p + 1), __ATOMIC_RELEASE, __HIP_MEMORY_SCOPE_AGENT);
    }
  }

  gbar_full(bar);  // collect all lanes before the linear head

  // ---- final linear: out[b] = dot(h2_final[b,:], linW) + linb
  // (T even -> final h2 in h2f0)
  if (wg == 0) {
    float* rf = (float*)dynlds;
    const int tid = threadIdx.x;
    const int b = tid >> 2, qq = tid & 3;
    const float* row = h2f0 + (size_t)b * H_ + qq * 256;
    const float* w = linW + qq * 256;
    float s = 0.f;
    for (int k = 0; k < 256; k++) s += cloadf(&row[k]) * w[k];
    rf[tid] = s;
    __syncthreads();
    if (tid < B_)
      out[tid] = rf[tid * 4] + rf[tid * 4 + 1] + rf[tid * 4 + 2] + rf[tid * 4 + 3] + linb[0];
  }
}

extern "C" void kernel_launch(void* const* d_in, const int* in_sizes, int n_in,
                              void* d_out, int out_size, void* d_ws, size_t ws_size,
                              hipStream_t stream) {
  const float* in_seq = (const float*)d_in[0];
  const float* c1Q = (const float*)d_in[1];
  const float* c1Qb = (const float*)d_in[2];
  const float* c1R = (const float*)d_in[3];
  const float* c1Rb = (const float*)d_in[4];
  const float* c1Wih = (const float*)d_in[5];
  const float* c1Whh = (const float*)d_in[6];
  const float* c1bih = (const float*)d_in[7];
  const float* c1bhh = (const float*)d_in[8];
  const float* c2Q = (const float*)d_in[9];
  const float* c2Qb = (const float*)d_in[10];
  const float* c2R = (const float*)d_in[11];
  const float* c2Rb = (const float*)d_in[12];
  const float* c2Wih = (const float*)d_in[13];
  const float* c2Whh = (const float*)d_in[14];
  const float* c2bih = (const float*)d_in[15];
  const float* c2bhh = (const float*)d_in[16];
  const float* linW = (const float*)d_in[17];
  const float* linb = (const float*)d_in[18];

  static_assert(sizeof(GBar) == 8448, "gbar layout");
  static_assert(sizeof(GrpBar) == 768, "grpbar layout");
  static_assert(OFF_GRP + 16 * sizeof(GrpBar) <= OFF_FLG, "barrier region");
  static_assert(OFF_FLG + 2048 <= OFF_H1F, "flag region");
  static_assert(DYN_LDS == 53504, "lds layout");
  hipFuncSetAttribute((const void*)moglstm_kernel,
                      hipFuncAttributeMaxDynamicSharedMemorySize, (int)DYN_LDS);
  hipMemsetAsync(d_ws, 0, ZERO_BYTES, stream);
  moglstm_kernel<<<dim3(NWG), dim3(WGS), DYN_LDS, stream>>>(
      in_seq, c1Q, c1Qb, c1R, c1Rb, c1Wih, c1Whh, c1bih, c1bhh,
      c2Q, c2Qb, c2R, c2Rb, c2Wih, c2Whh, c2bih, c2bhh,
      linW, linb, (char*)d_ws, (float*)d_out);
}

// Round 7
// 61822.491 us; speedup vs baseline: 1.2177x; 1.2177x over previous
//
#include <hip/hip_runtime.h>

#define NWG 256
#define WGS 512

typedef __attribute__((ext_vector_type(4))) float facc4;
typedef __attribute__((ext_vector_type(8))) short bfrag8;

#define MFMA_BF16 __builtin_amdgcn_mfma_f32_16x16x32_bf16

constexpr int B_ = 128, T_ = 512, I_ = 128, H_ = 1024;
constexpr int G_ = 4 * H_;  // 4096

// ---------------- workspace layout (bytes) ----------------
constexpr size_t OFF_BAR  = 0;       // device-wide full barrier (init/final)
constexpr size_t OFF_PB2  = 4608;    // 8 x PB8  (L2 sets)      = 9216
constexpr size_t OFF_PB1  = 13824;   // 8 x PB8  (L1 sets)      = 9216
constexpr size_t OFF_PBA  = 23040;   // 8 x PB32 (full groups)  = 33792
constexpr size_t OFF_FS0  = 56832;   // 8 x 128B s0-done flags  = 1024
constexpr size_t OFF_H1F  = 57856;
constexpr size_t OFF_H2F  = OFF_H1F + 2ull * B_ * H_ * 4;
constexpr size_t OFF_C1   = OFF_H2F + 2ull * B_ * H_ * 4;
constexpr size_t OFF_C2   = OFF_C1 + (size_t)B_ * H_ * 4;
constexpr size_t OFF_X1F  = OFF_C2 + (size_t)B_ * H_ * 4;
constexpr size_t OFF_X2F  = OFF_X1F + (size_t)B_ * I_ * 4;
constexpr size_t OFF_H1S  = OFF_X2F + (size_t)B_ * H_ * 4;
constexpr size_t OFF_H2S  = OFF_H1S + 2ull * B_ * H_ * 2;
constexpr size_t OFF_X1S  = OFF_H2S + 2ull * B_ * H_ * 2;
constexpr size_t OFF_X2S  = OFF_X1S + (size_t)B_ * I_ * 2;
constexpr size_t OFF_BS1  = OFF_X2S + (size_t)B_ * H_ * 2;
constexpr size_t OFF_BS2  = OFF_BS1 + (size_t)G_ * 4;
constexpr size_t ZERO_BYTES = OFF_BS2 + (size_t)G_ * 4;
// bf16 weights (converted in-kernel each launch), L2/L3-resident afterwards
constexpr size_t OFF_WQ1  = ZERO_BYTES;                         // 3*I*H
constexpr size_t OFF_WR1  = OFF_WQ1 + 3ull * I_ * H_ * 2;       // 2*H*I
constexpr size_t OFF_WIH1 = OFF_WR1 + 2ull * H_ * I_ * 2;       // G*I
constexpr size_t OFF_WHH1 = OFF_WIH1 + (size_t)G_ * I_ * 2;     // G*H
constexpr size_t OFF_WQ2  = OFF_WHH1 + (size_t)G_ * H_ * 2;     // 3*H*H
constexpr size_t OFF_WR2  = OFF_WQ2 + 3ull * H_ * H_ * 2;       // 2*H*H
constexpr size_t OFF_WIH2 = OFF_WR2 + 2ull * H_ * H_ * 2;       // G*H
constexpr size_t OFF_WHH2 = OFF_WIH2 + (size_t)G_ * H_ * 2;     // G*H

// ---------------- dynamic LDS (verbatim round 5) ----------------
constexpr size_t A_OFF   = 0;                    // 16*2056*2 = 65792
constexpr size_t RED_OFF = 65792;                // 8*2*4*64*4 = 16384
constexpr size_t DYN_LDS = RED_OFF + 16384;      // 82176

struct GBar {
  unsigned leaf[32][32];
  unsigned root[32];
  unsigned gen[32];
};
// store/poll barriers: one 128B slot per WG (plain stores, no RMW),
// leader wave polls all slots with one vector load, then bumps gen.
struct PB8  { unsigned slot[8][32];  unsigned gen[32]; };   // 1152 B
struct PB32 { unsigned slot[32][32]; unsigned gen[32]; };   // 4224 B

__device__ __forceinline__ float sigf(float x) { return 1.0f / (1.0f + __expf(-x)); }

__device__ __forceinline__ unsigned short f2bf(float f) {
  union { float f; unsigned u; } v; v.f = f;
  unsigned r = v.u + 0x7FFFu + ((v.u >> 16) & 1u);  // RNE
  return (unsigned short)(r >> 16);
}

// ---------- device-coherent (sc0 sc1) data plane for cross-WG data ----------
__device__ __forceinline__ float cloadf(const float* p) {
  return __hip_atomic_load(p, __ATOMIC_RELAXED, __HIP_MEMORY_SCOPE_AGENT);
}
__device__ __forceinline__ unsigned cloadu_(const unsigned* p) {
  return __hip_atomic_load(p, __ATOMIC_RELAXED, __HIP_MEMORY_SCOPE_AGENT);
}
__device__ __forceinline__ void cstoref(float* p, float v) {
  __hip_atomic_store(p, v, __ATOMIC_RELAXED, __HIP_MEMORY_SCOPE_AGENT);
}
__device__ __forceinline__ void cstoreu(unsigned* p, unsigned v) {
  __hip_atomic_store(p, v, __ATOMIC_RELAXED, __HIP_MEMORY_SCOPE_AGENT);
}
// pack bf16 shadow pairs: even lane stores (v, neighbor v) as one u32
__device__ __forceinline__ void cstore_sh(unsigned short* base, size_t idx, float v, int lane) {
  float vo = __shfl_xor(v, 1);
  if (!(lane & 1)) {
    unsigned pk = (unsigned)f2bf(v) | ((unsigned)f2bf(vo) << 16);
    cstoreu((unsigned*)(base + idx), pk);
  }
}

// bulk coherent stage (activations): rows x (C4*4) bf16 -> LDS, whole WG
template <int C4>
__device__ __forceinline__ void stage_coh(unsigned short* lds, int ldsStride, int ldsColOff,
                                          const unsigned short* src, int srcStride, int rows) {
  const int total = rows * C4;
  for (int i = threadIdx.x; i < total; i += WGS) {
    int r = i / C4, q = (i % C4) * 4;
    unsigned long long v = __hip_atomic_load(
        (const unsigned long long*)(src + (size_t)r * srcStride + q),
        __ATOMIC_RELAXED, __HIP_MEMORY_SCOPE_AGENT);
    *(unsigned long long*)(lds + (size_t)r * ldsStride + ldsColOff + q) = v;
  }
}

// ---- store/poll barrier. Visibility argument identical to the proven tree
// barrier: the leading __syncthreads drains every wave's vmcnt (all coherent
// stores/loads complete, at L3) BEFORE the arrival store is issued; leader's
// gen store is issued only after it observed every arrival; consumers load
// data only after observing gen. All ops are agent-scope at the L3 point.
// Monotonic counters -> no reset races.
template <int N, typename PB>
__device__ __forceinline__ void pbar(PB* b, int idx, unsigned c) {
  __syncthreads();
  const int tid = threadIdx.x;
  if (tid == 0) cstoreu(&b->slot[idx][0], c);  // arrival: plain store, own line
  if (idx == 0 && tid < 64) {                  // leader WG, wave 0: detect+release
    for (;;) {
      unsigned v = c;
      if (tid < N) v = cloadu_(&b->slot[tid][0]);
      if (__ballot(v >= c) == ~0ull) break;
      __builtin_amdgcn_s_sleep(1);
    }
    if (tid == 0) cstoreu(&b->gen[0], c);
  }
  if (tid == 0) {
    while (cloadu_(&b->gen[0]) < c) __builtin_amdgcn_s_sleep(1);
    asm volatile("" ::: "memory");
  }
  __syncthreads();
}

// ---- one-way cross-set flag wait (L1 set waits for L2's s0 completion)
__device__ __forceinline__ void wait_flag(const unsigned* f, unsigned need) {
  if (threadIdx.x == 0) {
    while (cloadu_(f) < need) __builtin_amdgcn_s_sleep(1);
    asm volatile("" ::: "memory");
  }
  __syncthreads();
}

// ---- device-wide full-fence barrier: init (publish weights) + final collect
__device__ __forceinline__ void gbar_init(GBar* b) {
  __syncthreads();
  if (threadIdx.x == 0) {
    __builtin_amdgcn_fence(__ATOMIC_RELEASE, "agent");
    unsigned g = __hip_atomic_load(&b->gen[0], __ATOMIC_RELAXED, __HIP_MEMORY_SCOPE_AGENT);
    int leaf = blockIdx.x >> 3;
    unsigned a = __hip_atomic_fetch_add(&b->leaf[leaf][0], 1u, __ATOMIC_RELAXED,
                                        __HIP_MEMORY_SCOPE_AGENT);
    if (a == 7u) {
      unsigned r = __hip_atomic_fetch_add(&b->root[0], 1u, __ATOMIC_RELAXED,
                                          __HIP_MEMORY_SCOPE_AGENT);
      if (r == 31u) {
        for (int i = 0; i < 32; i++)
          __hip_atomic_store(&b->leaf[i][0], 0u, __ATOMIC_RELAXED, __HIP_MEMORY_SCOPE_AGENT);
        __hip_atomic_store(&b->root[0], 0u, __ATOMIC_RELAXED, __HIP_MEMORY_SCOPE_AGENT);
        __hip_atomic_store(&b->gen[0], g + 1u, __ATOMIC_RELEASE, __HIP_MEMORY_SCOPE_AGENT);
      }
    }
    while (__hip_atomic_load(&b->gen[0], __ATOMIC_RELAXED, __HIP_MEMORY_SCOPE_AGENT) == g)
      __builtin_amdgcn_s_sleep(1);
    __builtin_amdgcn_fence(__ATOMIC_ACQUIRE, "agent");
  }
  __syncthreads();
}

// ---- wave-local mog unit (round-4/5 verified, byte-identical)
template <int K>
__device__ __forceinline__ void mog_wl(
    const unsigned short* __restrict__ A,   // bf16 shadow, row stride K
    const unsigned short* __restrict__ W,   // N rows x K, plain-cached
    const float* __restrict__ bias,
    const float* srcF, int srcStride,
    float* dstF, unsigned short* dstS, int N,
    int mt, int ntBase, unsigned short* As) {
  const int tid = threadIdx.x, lane = tid & 63, wv = tid >> 6;
  const int l15 = lane & 15, lq = lane >> 4;
  const int nt = ntBase + wv, n = nt * 16 + l15;
  constexpr int LSTR = K + 8;
  float srcv[4];
#pragma unroll
  for (int j = 0; j < 4; j++)
    srcv[j] = cloadf(&srcF[(size_t)(mt * 16 + lq * 4 + j) * srcStride + n]);
  const float bn = bias[n];

  stage_coh<K / 4>(As, LSTR, 0, A + (size_t)(mt * 16) * K, K, 16);
  __syncthreads();

  const unsigned short* ap = As + l15 * LSTR + lq * 8;
  const unsigned short* wp = W + (size_t)n * K + lq * 8;
  facc4 acc = {0.f, 0.f, 0.f, 0.f};
#pragma unroll 8
  for (int k = 0; k < K; k += 32)
    acc = MFMA_BF16(*(const bfrag8*)(ap + k), *(const bfrag8*)(wp + k), acc, 0, 0, 0);
#pragma unroll
  for (int j = 0; j < 4; j++) {
    float v = 2.0f * sigf(acc[j] + bn) * srcv[j];
    const int m = mt * 16 + lq * 4 + j;
    cstoref(&dstF[(size_t)m * N + n], v);
    cstore_sh(dstS, (size_t)m * N + n, v, lane);
  }
  // trailing sync provided by the phase barrier
}

// ---- LSTM cell unit (round-4/5 verified, byte-identical)
template <int CELL>
__device__ __forceinline__ void cell_wl(
    const unsigned short* __restrict__ Xs,
    const unsigned short* __restrict__ Hs,
    const unsigned short* __restrict__ Wih,
    const unsigned short* __restrict__ Whh,
    const float* __restrict__ bsum,
    float* cst, float* hF, unsigned short* hS,
    int mt, int nb, unsigned short* As, float (*red)[2][4][64]) {
  constexpr int KX = (CELL == 1) ? 128 : 1024;
  constexpr int LSTR = KX + 1024 + 8;
  const int tid = threadIdx.x, lane = tid & 63, wv = tid >> 6;
  const int l15 = lane & 15, lq = lane >> 4;
  const int g = wv >> 1, nh = wv & 1;
  const int n0 = nb * 64 + nh * 32 + l15;
  const int n1 = n0 + 16;

  float cold[2][4];
  float bsv[2][4];
  if (g == 0) {
#pragma unroll
    for (int j = 0; j < 4; j++) {
      cold[0][j] = cloadf(&cst[(size_t)(mt * 16 + lq * 4 + j) * H_ + n0]);
      cold[1][j] = cloadf(&cst[(size_t)(mt * 16 + lq * 4 + j) * H_ + n1]);
    }
#pragma unroll
    for (int gg = 0; gg < 4; gg++) {
      bsv[0][gg] = bsum[gg * H_ + n0];
      bsv[1][gg] = bsum[gg * H_ + n1];
    }
  }

  stage_coh<KX / 4>(As, LSTR, 0, Xs + (size_t)(mt * 16) * KX, KX, 16);
  stage_coh<256>(As, LSTR, KX, Hs + (size_t)(mt * 16) * 1024, 1024, 16);
  __syncthreads();

  const unsigned short* ap = As + l15 * LSTR + lq * 8;
  const int wr0 = g * H_ + nb * 64 + nh * 32 + l15;
  const unsigned short* wi0 = Wih + (size_t)wr0 * KX + lq * 8;
  const unsigned short* wi1 = wi0 + (size_t)16 * KX;
  const unsigned short* wh0 = Whh + (size_t)wr0 * 1024 + lq * 8;
  const unsigned short* wh1 = wh0 + (size_t)16 * 1024;
  facc4 a0 = {0.f, 0.f, 0.f, 0.f}, a1 = {0.f, 0.f, 0.f, 0.f};
#pragma unroll 4
  for (int k = 0; k < KX; k += 32) {
    bfrag8 af = *(const bfrag8*)(ap + k);
    a0 = MFMA_BF16(af, *(const bfrag8*)(wi0 + k), a0, 0, 0, 0);
    a1 = MFMA_BF16(af, *(const bfrag8*)(wi1 + k), a1, 0, 0, 0);
  }
#pragma unroll 4
  for (int k = 0; k < 1024; k += 32) {
    bfrag8 af = *(const bfrag8*)(ap + KX + k);
    a0 = MFMA_BF16(af, *(const bfrag8*)(wh0 + k), a0, 0, 0, 0);
    a1 = MFMA_BF16(af, *(const bfrag8*)(wh1 + k), a1, 0, 0, 0);
  }
#pragma unroll
  for (int j = 0; j < 4; j++) { red[wv][0][j][lane] = a0[j]; red[wv][1][j][lane] = a1[j]; }
  __syncthreads();

  if (g == 0) {
#pragma unroll
    for (int tt = 0; tt < 2; tt++) {
      const int n = (tt == 0) ? n0 : n1;
#pragma unroll
      for (int j = 0; j < 4; j++) {
        float di = red[0 * 2 + nh][tt][j][lane];
        float df = red[1 * 2 + nh][tt][j][lane];
        float dg = red[2 * 2 + nh][tt][j][lane];
        float dd = red[3 * 2 + nh][tt][j][lane];
        float iv = sigf(di + bsv[tt][0]);
        float fv = sigf(df + bsv[tt][1]);
        float gv = tanhf(dg + bsv[tt][2]);
        float ov = sigf(dd + bsv[tt][3]);
        float cn = fv * cold[tt][j] + iv * gv;
        float hn = ov * tanhf(cn);
        const int m = mt * 16 + lq * 4 + j;
        const size_t idx = (size_t)m * H_ + n;
        cstoref(&cst[idx], cn);
        cstoref(&hF[idx], hn);
        cstore_sh(hS, idx, hn, lane);
      }
    }
  }
}

__global__ __launch_bounds__(WGS, 1) void moglstm_kernel(
    const float* __restrict__ in_seq,
    const float* __restrict__ c1Q, const float* __restrict__ c1Qb,
    const float* __restrict__ c1R, const float* __restrict__ c1Rb,
    const float* __restrict__ c1Wih, const float* __restrict__ c1Whh,
    const float* __restrict__ c1bih, const float* __restrict__ c1bhh,
    const float* __restrict__ c2Q, const float* __restrict__ c2Qb,
    const float* __restrict__ c2R, const float* __restrict__ c2Rb,
    const float* __restrict__ c2Wih, const float* __restrict__ c2Whh,
    const float* __restrict__ c2bih, const float* __restrict__ c2bhh,
    const float* __restrict__ linW, const float* __restrict__ linb,
    char* ws, float* __restrict__ out) {
  extern __shared__ char dynlds[];
  unsigned short* As = (unsigned short*)(dynlds + A_OFF);
  float (*red)[2][4][64] = reinterpret_cast<float(*)[2][4][64]>(dynlds + RED_OFF);

  GBar* bar = (GBar*)(ws + OFF_BAR);
  PB8*  pb2 = (PB8*)(ws + OFF_PB2);
  PB8*  pb1 = (PB8*)(ws + OFF_PB1);
  PB32* pba = (PB32*)(ws + OFF_PBA);
  unsigned* fS0 = (unsigned*)(ws + OFF_FS0);   // [8][32]
  float* h1f0 = (float*)(ws + OFF_H1F);
  float* h1f1 = h1f0 + (size_t)B_ * H_;
  float* h2f0 = (float*)(ws + OFF_H2F);
  float* h2f1 = h2f0 + (size_t)B_ * H_;
  float* c1f = (float*)(ws + OFF_C1);
  float* c2f = (float*)(ws + OFF_C2);
  float* x1f = (float*)(ws + OFF_X1F);
  float* x2f = (float*)(ws + OFF_X2F);
  unsigned short* h1s0 = (unsigned short*)(ws + OFF_H1S);
  unsigned short* h1s1 = h1s0 + (size_t)B_ * H_;
  unsigned short* h2s0 = (unsigned short*)(ws + OFF_H2S);
  unsigned short* h2s1 = h2s0 + (size_t)B_ * H_;
  unsigned short* x1s = (unsigned short*)(ws + OFF_X1S);
  unsigned short* x2s = (unsigned short*)(ws + OFF_X2S);
  float* bs1 = (float*)(ws + OFF_BS1);
  float* bs2 = (float*)(ws + OFF_BS2);
  unsigned short* wq1 = (unsigned short*)(ws + OFF_WQ1);
  unsigned short* wr1 = (unsigned short*)(ws + OFF_WR1);
  unsigned short* wih1 = (unsigned short*)(ws + OFF_WIH1);
  unsigned short* whh1 = (unsigned short*)(ws + OFF_WHH1);
  unsigned short* wq2 = (unsigned short*)(ws + OFF_WQ2);
  unsigned short* wr2 = (unsigned short*)(ws + OFF_WR2);
  unsigned short* wih2 = (unsigned short*)(ws + OFF_WIH2);
  unsigned short* whh2 = (unsigned short*)(ws + OFF_WHH2);

  const int wg = blockIdx.x;
  const int grp = wg >> 5;     // mt-group: owns batch rows [grp*16, grp*16+16)
  const int l = wg & 31;       // local id within group

  // ---- init: fp32 -> bf16 weight conversion (plain stores) + bias sums
  {
    size_t gt = (size_t)wg * WGS + threadIdx.x;
    const size_t gs = (size_t)NWG * WGS;
    const float* srcs[8] = {c1Q, c1R, c1Wih, c1Whh, c2Q, c2R, c2Wih, c2Whh};
    unsigned short* dsts[8] = {wq1, wr1, wih1, whh1, wq2, wr2, wih2, whh2};
    const size_t cnts[8] = {3ull * I_ * H_, 2ull * H_ * I_, (size_t)G_ * I_,
                            (size_t)G_ * H_, 3ull * H_ * H_, 2ull * H_ * H_,
                            (size_t)G_ * H_, (size_t)G_ * H_};
    for (int a = 0; a < 8; a++)
      for (size_t i = gt; i < cnts[a]; i += gs) dsts[a][i] = f2bf(srcs[a][i]);
    for (size_t i = gt; i < (size_t)G_; i += gs) bs1[i] = c1bih[i] + c1bhh[i];
    for (size_t i = gt; i < (size_t)G_; i += gs) bs2[i] = c2bih[i] + c2bhh[i];
  }
  gbar_init(bar);  // full fences ONCE: publish plain-stored weights

  // Role map within a group (round-5 verified):
  //   mog2  (s<5): l 0..7   (L2 set)   mog1Q (s even): l==8 | mog1R (s odd): l 8..15 (L1 set)
  //   cell1 (s5):  l 0..15             cell2 (s5): l 16..31
  // Sync domains: s0..s4 -> per-set 8-WG pbar; s5 entry/exit -> 32-WG pbar.
  // Cross-set edge: L2.s0 READS h1q; L1.s1 WRITES h1q in place -> fS0 flag.
  PB8*  myPb2 = &pb2[grp];
  PB8*  myPb1 = &pb1[grp];
  PB32* myPba = &pba[grp];
  unsigned* myF = fS0 + grp * 32;
  unsigned cSet = 0, cAll = 0;

  for (int p = 0; p <= T_; ++p) {
    const int q = p & 1;
    const int q2 = 1 - q;
    const bool doL1 = (p < T_);
    const bool doL2 = (p > 0);
    float* h1q = q ? h1f1 : h1f0;
    float* h1o = q ? h1f0 : h1f1;
    unsigned short* h1sq = q ? h1s1 : h1s0;
    unsigned short* h1so = q ? h1s0 : h1s1;
    float* h2q2 = q2 ? h2f1 : h2f0;
    float* h2o = q ? h2f1 : h2f0;
    unsigned short* h2sq2 = q2 ? h2s1 : h2s0;
    unsigned short* h2so = q ? h2s1 : h2s0;

    if (l < 16) {
      for (int s = 0; s < 5; ++s) {
        const int r = s >> 1;
        if (s & 1) {  // R rounds
          if (l >= 8) wait_flag(myF, (unsigned)(p + 1));  // L2.s0 read of h1q done
          if (doL2 && l < 8)
            mog_wl<1024>(x2s, wr2 + (size_t)r * H_ * H_, c2Rb + r * H_,
                         h2q2, H_, h2q2, h2sq2, H_, grp, l * 8, As);
          if (doL1 && l >= 8)
            mog_wl<128>(x1s, wr1 + (size_t)r * H_ * I_, c1Rb + r * H_,
                        h1q, H_, h1q, h1sq, H_, grp, (l - 8) * 8, As);
        } else {      // Q rounds
          if (doL2 && l < 8)
            mog_wl<1024>(h2sq2, wq2 + (size_t)r * H_ * H_, c2Qb + r * H_,
                         (r == 0) ? h1q : x2f, H_, x2f, x2s, H_, grp, l * 8, As);
          if (doL1 && l == 8)
            mog_wl<1024>(h1sq, wq1 + (size_t)r * I_ * H_, c1Qb + r * I_,
                         (r == 0) ? (in_seq + (size_t)p * I_) : x1f,
                         (r == 0) ? T_ * I_ : I_, x1f, x1s, I_, grp, 0, As);
        }
        ++cSet;
        if (l < 8) pbar<8>(myPb2, l, cSet);
        else       pbar<8>(myPb1, l - 8, cSet);
        if (s == 0 && l == 0 && threadIdx.x == 0)
          cstoreu(myF, (unsigned)(p + 1));  // release h1q for L1's in-place R0
      }
    }
    // ---- s5 entry: full-group sync (cells consume both sets' products)
    ++cAll; pbar<32>(myPba, l, cAll);
    if (doL1 && l < 16)
      cell_wl<1>(x1s, h1sq, wih1, whh1, bs1, c1f, h1o, h1so, grp, l, As, red);
    if (doL2 && l >= 16)
      cell_wl<2>(x2s, h2sq2, wih2, whh2, bs2, c2f, h2o, h2so, grp, l - 16, As, red);
    ++cAll; pbar<32>(myPba, l, cAll);
  }

  gbar_init(bar);  // collect all groups before the linear head

  // ---- final linear: out[b] = dot(h2_final[b,:], linW) + linb (parity 0)
  if (wg == 0) {
    float* rf = (float*)dynlds;
    const int tid = threadIdx.x;
    const int b = tid >> 2, qq = tid & 3;
    const float* row = h2f0 + (size_t)b * H_ + qq * 256;
    const float* w = linW + qq * 256;
    float s = 0.f;
    for (int k = 0; k < 256; k++) s += cloadf(&row[k]) * w[k];
    rf[tid] = s;
    __syncthreads();
    if (tid < B_)
      out[tid] = rf[tid * 4] + rf[tid * 4 + 1] + rf[tid * 4 + 2] + rf[tid * 4 + 3] + linb[0];
  }
}

extern "C" void kernel_launch(void* const* d_in, const int* in_sizes, int n_in,
                              void* d_out, int out_size, void* d_ws, size_t ws_size,
                              hipStream_t stream) {
  const float* in_seq = (const float*)d_in[0];
  const float* c1Q = (const float*)d_in[1];
  const float* c1Qb = (const float*)d_in[2];
  const float* c1R = (const float*)d_in[3];
  const float* c1Rb = (const float*)d_in[4];
  const float* c1Wih = (const float*)d_in[5];
  const float* c1Whh = (const float*)d_in[6];
  const float* c1bih = (const float*)d_in[7];
  const float* c1bhh = (const float*)d_in[8];
  const float* c2Q = (const float*)d_in[9];
  const float* c2Qb = (const float*)d_in[10];
  const float* c2R = (const float*)d_in[11];
  const float* c2Rb = (const float*)d_in[12];
  const float* c2Wih = (const float*)d_in[13];
  const float* c2Whh = (const float*)d_in[14];
  const float* c2bih = (const float*)d_in[15];
  const float* c2bhh = (const float*)d_in[16];
  const float* linW = (const float*)d_in[17];
  const float* linb = (const float*)d_in[18];

  static_assert(sizeof(PB8) == 1152, "pb8 layout");
  static_assert(sizeof(PB32) == 4224, "pb32 layout");
  static_assert(OFF_PB2 + 8 * sizeof(PB8) <= OFF_PB1, "pb2 region");
  static_assert(OFF_PB1 + 8 * sizeof(PB8) <= OFF_PBA, "pb1 region");
  static_assert(OFF_PBA + 8 * sizeof(PB32) <= OFF_FS0, "pba region");
  static_assert(OFF_FS0 + 1024 <= OFF_H1F, "flag region");
  static_assert(DYN_LDS == 82176, "lds layout");
  hipFuncSetAttribute((const void*)moglstm_kernel,
                      hipFuncAttributeMaxDynamicSharedMemorySize, (int)DYN_LDS);
  hipMemsetAsync(d_ws, 0, ZERO_BYTES, stream);
  moglstm_kernel<<<dim3(NWG), dim3(WGS), DYN_LDS, stream>>>(
      in_seq, c1Q, c1Qb, c1R, c1Rb, c1Wih, c1Whh, c1bih, c1bhh,
      c2Q, c2Qb, c2R, c2Rb, c2Wih, c2Whh, c2bih, c2bhh,
      linW, linb, (char*)d_ws, (float*)d_out);
}